// Round 1
// baseline (1005.611 us; speedup 1.0000x reference)
//
#include <hip/hip_runtime.h>
#include <math.h>

#define U_NUM_ 50000
#define I_NUM_ 50000
#define EMBED_ 64
#define ATT_   64
#define NNZ_   2500000

// ---------------------------------------------------------------------------
// Pass 0: four 50000x64 @ 64x64^T projections. W cached in LDS (padded).
// combo 0: Qu = user @ Wq^T + bq
// combo 1: Ki = item @ Wk^T + bk
// combo 2: Qi = item @ Wq^T + bq
// combo 3: Ku = user @ Wk^T + bk
// ---------------------------------------------------------------------------
__global__ void proj_kernel(const float* __restrict__ user_embed,
                            const float* __restrict__ item_embed,
                            const float* __restrict__ Wq, const float* __restrict__ bq,
                            const float* __restrict__ Wk, const float* __restrict__ bk,
                            float* __restrict__ proj) {
    __shared__ float Wl[ATT_][EMBED_ + 1];   // +1 pad: avoid 64-way bank conflict
    __shared__ float bl[ATT_];
    const int combo = blockIdx.y;
    const float* E = (combo == 0 || combo == 3) ? user_embed : item_embed;
    const float* W = (combo == 0 || combo == 2) ? Wq : Wk;
    const float* b = (combo == 0 || combo == 2) ? bq : bk;
    float* out = proj + (size_t)combo * U_NUM_ * ATT_;

    for (int i = threadIdx.x; i < ATT_ * EMBED_; i += blockDim.x)
        Wl[i >> 6][i & 63] = W[i];
    if (threadIdx.x < ATT_) bl[threadIdx.x] = b[threadIdx.x];
    __syncthreads();

    const int a  = threadIdx.x & 63;   // output feature
    const int rl = threadIdx.x >> 6;   // 0..3 local row
    const int row0 = blockIdx.x * 64;
    for (int r = row0 + rl; r < row0 + 64 && r < U_NUM_; r += 4) {
        const float4* Erow = (const float4*)(E + (size_t)r * EMBED_);
        float acc = bl[a];
        #pragma unroll
        for (int e4 = 0; e4 < EMBED_ / 4; ++e4) {
            float4 ev = Erow[e4];
            acc += ev.x * Wl[a][e4 * 4 + 0];
            acc += ev.y * Wl[a][e4 * 4 + 1];
            acc += ev.z * Wl[a][e4 * 4 + 2];
            acc += ev.w * Wl[a][e4 * 4 + 3];
        }
        out[(size_t)r * ATT_ + a] = acc;
    }
}

// ---------------------------------------------------------------------------
// Pass 1: per-edge w = Q[q]·K[k]; e = exp(w - log(-log(u))); atomicAdd segsum.
// 16 lanes per edge: each lane loads one float4 of Q and K (coalesced 256B),
// shfl_xor reduce within the 16-lane group.
// Edge index g in [0, 2*NNZ): g < NNZ -> ui block, else iu block.
// Max-subtraction skipped: v is analytically bounded (|v| <= ~31), exp fits f32.
// ---------------------------------------------------------------------------
__global__ void edge_pass1(const int* __restrict__ rows, const int* __restrict__ cols,
                           const float* __restrict__ u_ui, const float* __restrict__ u_iu,
                           const float* __restrict__ proj,
                           float* __restrict__ out, float* __restrict__ segsum) {
    const float* Qu = proj + 0 * (size_t)U_NUM_ * ATT_;
    const float* Ki = proj + 1 * (size_t)U_NUM_ * ATT_;
    const float* Qi = proj + 2 * (size_t)U_NUM_ * ATT_;
    const float* Ku = proj + 3 * (size_t)U_NUM_ * ATT_;

    const int lane = threadIdx.x & 15;
    int g      = (blockIdx.x * blockDim.x + threadIdx.x) >> 4;
    const int stride = (gridDim.x * blockDim.x) >> 4;

    for (; g < 2 * NNZ_; g += stride) {
        int q_idx, k_idx, seg_off;
        const float *Q, *K;
        float u;
        if (g < NNZ_) {
            q_idx = rows[g]; k_idx = cols[g];
            Q = Qu; K = Ki; u = u_ui[g]; seg_off = 0;
        } else {
            int j = g - NNZ_;
            q_idx = cols[j]; k_idx = rows[j];
            Q = Qi; K = Ku; u = u_iu[j]; seg_off = U_NUM_;
        }
        float4 qv = ((const float4*)(Q + (size_t)q_idx * ATT_))[lane];
        float4 kv = ((const float4*)(K + (size_t)k_idx * ATT_))[lane];
        float p = qv.x * kv.x + qv.y * kv.y + qv.z * kv.z + qv.w * kv.w;
        p += __shfl_xor(p, 1);
        p += __shfl_xor(p, 2);
        p += __shfl_xor(p, 4);
        p += __shfl_xor(p, 8);
        if (lane == 0) {
            float gq = logf(-logf(u));      // gumbel term
            float ee = expf(p - gq);        // TAU = 1
            out[g] = ee;
            atomicAdd(&segsum[seg_off + q_idx], ee);
        }
    }
}

// ---------------------------------------------------------------------------
// Pass 2: normalize by segment sum.
// ---------------------------------------------------------------------------
__global__ void edge_pass2(const int* __restrict__ rows, const int* __restrict__ cols,
                           const float* __restrict__ segsum, float* __restrict__ out) {
    int i = blockIdx.x * blockDim.x + threadIdx.x;
    const int stride = gridDim.x * blockDim.x;
    for (; i < 2 * NNZ_; i += stride) {
        int seg;
        if (i < NNZ_) seg = rows[i];
        else          seg = U_NUM_ + cols[i - NNZ_];
        out[i] = out[i] / segsum[seg];
    }
}

extern "C" void kernel_launch(void* const* d_in, const int* in_sizes, int n_in,
                              void* d_out, int out_size, void* d_ws, size_t ws_size,
                              hipStream_t stream) {
    const float* user_embed = (const float*)d_in[0];
    const float* item_embed = (const float*)d_in[1];
    const float* Wq = (const float*)d_in[2];
    const float* bq = (const float*)d_in[3];
    const float* Wk = (const float*)d_in[4];
    const float* bk = (const float*)d_in[5];
    const int*   rows = (const int*)d_in[6];
    const int*   cols = (const int*)d_in[7];
    const float* u_ui = (const float*)d_in[8];
    const float* u_iu = (const float*)d_in[9];
    float* out = (float*)d_out;

    float* proj   = (float*)d_ws;                                  // 4*50000*64 f32 = 51.2 MB
    float* segsum = proj + 4 * (size_t)U_NUM_ * ATT_;              // 100000 f32

    // zero the segment sums (accumulated via atomics each launch)
    hipMemsetAsync(segsum, 0, (U_NUM_ + I_NUM_) * sizeof(float), stream);

    dim3 pgrid((U_NUM_ + 63) / 64, 4);
    proj_kernel<<<pgrid, 256, 0, stream>>>(user_embed, item_embed, Wq, bq, Wk, bk, proj);

    edge_pass1<<<2048, 256, 0, stream>>>(rows, cols, u_ui, u_iu, proj, out, segsum);
    edge_pass2<<<2048, 256, 0, stream>>>(rows, cols, segsum, out);
}